// Round 2
// baseline (561.123 us; speedup 1.0000x reference)
//
#include <hip/hip_runtime.h>
#include <hip/hip_fp16.h>
#include <float.h>

#define MKEY 256        // K (key size)
#define NMEM 100000     // memory rows
#define NPAD 100096     // 782 * 128
#define NQ   2048       // queries
#define BM 128
#define BN 128
#define NTILES 782      // NPAD / BN
#define MTILES 16       // NQ / BM
#define GRID (128 * 98) // XCD-clustered id space; ntile>=782 early-exits
#define KEYBLOCKS (NPAD / 4)   // 25024
#define QS (127.0f / 6.0f)     // i8 quant scale (data ~N(0,1), clamp at 6 sigma)
#define SS2 ((6.0f / 127.0f) * (6.0f / 127.0f))  // dequant: dot_f = dot_i8 * SS2

typedef int i32x4 __attribute__((ext_vector_type(4)));

__device__ inline void gll16(const void* g, void* l) {
  __builtin_amdgcn_global_load_lds(
      (const __attribute__((address_space(1))) unsigned*)g,
      (__attribute__((address_space(3))) unsigned*)l, 16, 0, 0);
}

__device__ inline int pack_i8x4(float4 v) {
  int c0 = max(-127, min(127, __float2int_rn(v.x * QS)));
  int c1 = max(-127, min(127, __float2int_rn(v.y * QS)));
  int c2 = max(-127, min(127, __float2int_rn(v.z * QS)));
  int c3 = max(-127, min(127, __float2int_rn(v.w * QS)));
  return (c0 & 255) | ((c1 & 255) << 8) | ((c2 & 255) << 16) | ((c3 & 255) << 24);
}

// merged: keys fp32 -> i8 + inv key norm (fp32-exact) in blocks 0..25023;
// queries fp32 -> i8 in blocks 25024..25535
__global__ void convert(const float* __restrict__ q, const float* __restrict__ mem,
                        int* __restrict__ qi, int* __restrict__ ki,
                        float* __restrict__ rkn) {
  const int b = blockIdx.x;
  if (b >= KEYBLOCKS) {
    const int i = (b - KEYBLOCKS) * 256 + threadIdx.x;   // int4-group index
    const float4 v = *(const float4*)&q[(size_t)i * 4];
    qi[i] = pack_i8x4(v);
    return;
  }
  const int t = threadIdx.x, lane = t & 63, w = t >> 6;
  const int row = b * 4 + w;
  if (row < NMEM) {
    const float4 v = *(const float4*)&mem[(long)row * 512 + lane * 4];
    const float ss0 = v.x * v.x + v.y * v.y + v.z * v.z + v.w * v.w;
    ki[(size_t)row * 64 + lane] = pack_i8x4(v);
    float ss = ss0;
#pragma unroll
    for (int off = 32; off >= 1; off >>= 1) ss += __shfl_xor(ss, off, 64);
    if (lane == 0) rkn[row] = 1.0f / sqrtf(fmaxf(ss, 1e-30f));
  } else {
    ki[(size_t)row * 64 + lane] = 0;
    if (lane == 0) rkn[row] = 0.f;
  }
}

// Pass 1: i8 screening GEMM (mfma_i32_16x16x64_i8, 2x f16 rate, half the
// staged bytes). 128x128 tile, 4 waves, 4 blocks/CU (inter-block TLP hides
// stage latency — the proven structure for this short-K shape). LDS rows are
// 128 B with chunk-XOR swizzle (chunk ^= row&7), pre-applied to the gll16
// global source (rule #21): bank conflicts ~0 (verified round 1: 5.0e4).
// Writes per-(query, ntile) max score transposed: bmaxT[ntile * NQ + query].
__global__ __launch_bounds__(256, 4) void gemm_screen(
    const int* __restrict__ qi, const int* __restrict__ ki,
    const float* __restrict__ rkn, float* __restrict__ bmaxT) {
  __shared__ __align__(128) char Ab[BM * 128];   // 128 rows x 128 i8 (one K-step)
  __shared__ __align__(128) char Bb[BN * 128];
  __shared__ float cand[BM][2];

  // XCD-clustered decode: same-ntile blocks land on the same XCD (ids = mod 8)
  const int id = blockIdx.x;
  const int mtile = (id >> 3) & 15;
  const int ntile = (id & 7) + 8 * (id >> 7);
  if (ntile >= NTILES) return;

  const int t = threadIdx.x;
  const int w = t >> 6;
  const int lane = t & 63;
  const int wr = w >> 1, wc = w & 1;
  const int q16 = lane >> 4, l16 = lane & 15;
  const int l8 = lane >> 3, c8 = lane & 7;

  // staging: waves 0,1 -> Ab; waves 2,3 -> Bb; each wave 64 rows = 8 gll16.
  // call c covers rows (w&1)*64 + c*8 .. +7; lane l -> row +l8, phys chunk c8,
  // which must hold global chunk c8 ^ (row&7) = c8 ^ l8 (rows 8-aligned).
  const int swz = (c8 ^ l8) * 16;
  int soff[8];
#pragma unroll
  for (int c = 0; c < 8; ++c)
    soff[c] = ((w & 1) * 64 + c * 8 + l8) * 256 + swz;   // bytes (row stride 256B)
  const char* asrc = (const char*)((w < 2) ? qi : ki) +
                     (size_t)(((w < 2) ? mtile : ntile) * 128) * 256;
  char* adst = ((w < 2) ? Ab : Bb) + (w & 1) * 8192;

  i32x4 acc[4][4];
#pragma unroll
  for (int i = 0; i < 4; i++)
#pragma unroll
    for (int j = 0; j < 4; j++) acc[i][j] = (i32x4){0, 0, 0, 0};

  // phys chunk per ks: logical chunk = ks*4 + q16, xor row&7 = l16&7
  int pc[2];
#pragma unroll
  for (int ks = 0; ks < 2; ++ks) pc[ks] = (((ks * 4 + q16) ^ (l16 & 7))) * 16;

#pragma unroll
  for (int s = 0; s < 2; ++s) {            // 2 K-steps of 128
    __syncthreads();
#pragma unroll
    for (int c = 0; c < 8; ++c)
      gll16(asrc + s * 128 + soff[c], adst + c * 1024);
    __syncthreads();
#pragma unroll
    for (int ks = 0; ks < 2; ++ks) {
      i32x4 av[4], bv[4];
#pragma unroll
      for (int i = 0; i < 4; i++)
        av[i] = *(const i32x4*)&Ab[(64 * wr + 16 * i + l16) * 128 + pc[ks]];
#pragma unroll
      for (int j = 0; j < 4; j++)
        bv[j] = *(const i32x4*)&Bb[(64 * wc + 16 * j + l16) * 128 + pc[ks]];
#pragma unroll
      for (int i = 0; i < 4; i++)
#pragma unroll
        for (int j = 0; j < 4; j++)
          acc[i][j] = __builtin_amdgcn_mfma_i32_16x16x64_i8(av[i], bv[j], acc[i][j], 0, 0, 0);
    }
  }

  // Epilogue: per-query-row max of (i32 dot * S^2) * (1/kn) over 128 keys
  int ncol[4];
  float rk[4];
#pragma unroll
  for (int j = 0; j < 4; j++) {
    ncol[j] = ntile * BN + 64 * wc + 16 * j + l16;
    rk[j] = (ncol[j] < NMEM) ? rkn[ncol[j]] * SS2 : 0.f;
  }
#pragma unroll
  for (int i = 0; i < 4; i++) {
#pragma unroll
    for (int r = 0; r < 4; r++) {
      float m = -FLT_MAX;
#pragma unroll
      for (int j = 0; j < 4; j++)
        if (ncol[j] < NMEM) m = fmaxf(m, (float)acc[i][j][r] * rk[j]);
#pragma unroll
      for (int off = 1; off < 16; off <<= 1)
        m = fmaxf(m, __shfl_xor(m, off, 64));
      if (l16 == 0) cand[64 * wr + 16 * i + 4 * q16 + r][wc] = m;
    }
  }
  __syncthreads();
  if (t < BM) {
    float v = fmaxf(cand[t][0], cand[t][1]);
    bmaxT[(size_t)ntile * NQ + mtile * BM + t] = v;  // coalesced
  }
}

// Pass 2: per query, find qualifying blocks, exact double rescore, gather values.
// i8 screen: per-row score error std ~0.0175*qn, max over 2e8 rows ~0.109*qn/16;
// margin 1.8e-2*qn > 2x the 6.2-sigma bound (0.218) with 32% headroom.
__global__ __launch_bounds__(256) void rescore_gather(
    const float* __restrict__ q, const float* __restrict__ mem,
    const float* __restrict__ bmaxT, float* __restrict__ out) {
  __shared__ float red2[4];
  __shared__ int list[64];
  __shared__ int nlist;
  __shared__ double wb[4];
  __shared__ int wbi[4];
  __shared__ int widx;

  const int qi = blockIdx.x;
  const int t = threadIdx.x, w = t >> 6, lane = t & 63;
  const int r4 = lane >> 4, d16 = lane & 15;

  // this lane's 16 query dims, in registers once
  float4 q4[4];
#pragma unroll
  for (int c = 0; c < 4; ++c)
    q4[c] = *(const float4*)&q[(size_t)qi * 256 + d16 * 16 + c * 4];

  // ||q||: each dim covered by 4 lanes (r4 groups) -> wave sum = 4*||q||^2
  float ss = 0.f;
#pragma unroll
  for (int c = 0; c < 4; ++c)
    ss += q4[c].x * q4[c].x + q4[c].y * q4[c].y + q4[c].z * q4[c].z + q4[c].w * q4[c].w;
#pragma unroll
  for (int off = 32; off >= 1; off >>= 1) ss += __shfl_xor(ss, off, 64);
  const float qn = sqrtf(ss * 0.25f);
  const float margin = 1.8e-2f * qn;

  if (t == 0) nlist = 0;

  // global screened max over block maxima
  float gm = -FLT_MAX;
  for (int i = t; i < NTILES; i += 256) gm = fmaxf(gm, bmaxT[(size_t)i * NQ + qi]);
#pragma unroll
  for (int off = 32; off >= 1; off >>= 1) gm = fmaxf(gm, __shfl_xor(gm, off, 64));
  if (lane == 0) red2[w] = gm;
  __syncthreads();
  gm = fmaxf(fmaxf(red2[0], red2[1]), fmaxf(red2[2], red2[3]));
  const float thresh = gm - margin;

  for (int i = t; i < NTILES; i += 256)
    if (bmaxT[(size_t)i * NQ + qi] >= thresh) {
      int p = atomicAdd(&nlist, 1);
      if (p < 64) list[p] = i;
    }
  __syncthreads();
  const int nl = min(nlist, 64);

  double bestv = -1e300;
  int bestidx = 0x7fffffff;
  for (int c = 0; c < nl; ++c) {
    const int nt = list[c];
#pragma unroll 2
    for (int pass = 0; pass < 8; ++pass) {
      const int row = nt * 128 + w * 32 + pass * 4 + r4;
      double d = 0.0, s2 = 0.0;
      if (row < NMEM) {
#pragma unroll
        for (int c4 = 0; c4 < 4; ++c4) {
          const float4 kv = *(const float4*)&mem[(size_t)row * 512 + d16 * 16 + c4 * 4];
          d += (double)kv.x * q4[c4].x + (double)kv.y * q4[c4].y +
               (double)kv.z * q4[c4].z + (double)kv.w * q4[c4].w;
          s2 += (double)kv.x * kv.x + (double)kv.y * kv.y +
                (double)kv.z * kv.z + (double)kv.w * kv.w;
        }
      }
#pragma unroll
      for (int off = 1; off < 16; off <<= 1) {
        d += __shfl_xor(d, off, 64);
        s2 += __shfl_xor(s2, off, 64);
      }
      if (d16 == 0 && row < NMEM) {
        const double score = d / sqrt(s2 > 1e-300 ? s2 : 1e-300);
        if (score > bestv || (score == bestv && row < bestidx)) {
          bestv = score;
          bestidx = row;
        }
      }
    }
  }
  // cross-lane argmax (lanes with d16!=0 hold -1e300)
#pragma unroll
  for (int off = 1; off < 64; off <<= 1) {
    const double ov = __shfl_xor(bestv, off, 64);
    const int oi = __shfl_xor(bestidx, off, 64);
    if (ov > bestv || (ov == bestv && oi < bestidx)) {
      bestv = ov;
      bestidx = oi;
    }
  }
  if (lane == 0) { wb[w] = bestv; wbi[w] = bestidx; }
  __syncthreads();
  if (t == 0) {
    double bv = wb[0];
    int bi = wbi[0];
#pragma unroll
    for (int w2 = 1; w2 < 4; ++w2)
      if (wb[w2] > bv || (wb[w2] == bv && wbi[w2] < bi)) {
        bv = wb[w2];
        bi = wbi[w2];
      }
    widx = bi;
  }
  __syncthreads();
  out[(size_t)qi * 256 + t] = mem[(size_t)widx * 512 + 256 + t];
}

extern "C" void kernel_launch(void* const* d_in, const int* in_sizes, int n_in,
                              void* d_out, int out_size, void* d_ws, size_t ws_size,
                              hipStream_t stream) {
  const float* query = (const float*)d_in[0];
  const float* memory = (const float*)d_in[1];
  float* out = (float*)d_out;

  char* p = (char*)d_ws;
  int* qi = (int*)p; p += (size_t)NQ * 64 * 4;          // 2048 x 256 i8
  int* ki = (int*)p; p += (size_t)NPAD * 64 * 4;        // 100096 x 256 i8
  float* rkn = (float*)p; p += (size_t)NPAD * 4;
  float* bmaxT = (float*)p; p += (size_t)NQ * NTILES * 4;

  hipLaunchKernelGGL(convert, dim3(KEYBLOCKS + NQ * MKEY / 1024), dim3(256), 0, stream,
                     query, memory, qi, ki, rkn);
  hipLaunchKernelGGL(gemm_screen, dim3(GRID), dim3(256), 0, stream, qi, ki, rkn, bmaxT);
  hipLaunchKernelGGL(rescore_gather, dim3(NQ), dim3(256), 0, stream,
                     query, memory, bmaxT, out);
}

// Round 3
// 421.875 us; speedup vs baseline: 1.3301x; 1.3301x over previous
//
#include <hip/hip_runtime.h>
#include <hip/hip_fp16.h>
#include <float.h>

#define MKEY 256        // K (key size)
#define NMEM 100000     // memory rows
#define NPAD 100096     // 782 * 128
#define NQ   2048       // queries
#define BM 128
#define BN 128
#define NTILES 782      // NPAD / BN
#define MTILES 16       // NQ / BM
#define GRID (128 * 98) // XCD-clustered id space; ntile>=782 early-exits
#define KEYBLOCKS (NPAD / 4)   // 25024
#define QS (127.0f / 6.0f)     // i8 quant scale (data ~N(0,1), clamp at 6 sigma)
#define SS2 ((6.0f / 127.0f) * (6.0f / 127.0f))  // dequant: dot_f = dot_i8 * SS2

typedef int i32x4 __attribute__((ext_vector_type(4)));

__device__ inline void gll16(const void* g, void* l) {
  __builtin_amdgcn_global_load_lds(
      (const __attribute__((address_space(1))) unsigned*)g,
      (__attribute__((address_space(3))) unsigned*)l, 16, 0, 0);
}

__device__ inline int pack_i8x4(float4 v) {
  int c0 = max(-127, min(127, __float2int_rn(v.x * QS)));
  int c1 = max(-127, min(127, __float2int_rn(v.y * QS)));
  int c2 = max(-127, min(127, __float2int_rn(v.z * QS)));
  int c3 = max(-127, min(127, __float2int_rn(v.w * QS)));
  return (c0 & 255) | ((c1 & 255) << 8) | ((c2 & 255) << 16) | ((c3 & 255) << 24);
}

// signed 4x i8 dot (manual sign-extend; compile-safe, compiler may fuse to v_dot4)
__device__ inline int dot4i8(int a, int b) {
  int s = 0;
#pragma unroll
  for (int k = 0; k < 4; ++k) {
    const int av = (a << (24 - 8 * k)) >> 24;
    const int bv = (b << (24 - 8 * k)) >> 24;
    s += av * bv;
  }
  return s;
}

// merged: keys fp32 -> i8 + inv key norm (fp32-exact) in blocks 0..25023;
// queries fp32 -> i8 in blocks 25024..25535
__global__ void convert(const float* __restrict__ q, const float* __restrict__ mem,
                        int* __restrict__ qi, int* __restrict__ ki,
                        float* __restrict__ rkn) {
  const int b = blockIdx.x;
  if (b >= KEYBLOCKS) {
    const int i = (b - KEYBLOCKS) * 256 + threadIdx.x;   // int4-group index
    const float4 v = *(const float4*)&q[(size_t)i * 4];
    qi[i] = pack_i8x4(v);
    return;
  }
  const int t = threadIdx.x, lane = t & 63, w = t >> 6;
  const int row = b * 4 + w;
  if (row < NMEM) {
    const float4 v = *(const float4*)&mem[(long)row * 512 + lane * 4];
    const float ss0 = v.x * v.x + v.y * v.y + v.z * v.z + v.w * v.w;
    ki[(size_t)row * 64 + lane] = pack_i8x4(v);
    float ss = ss0;
#pragma unroll
    for (int off = 32; off >= 1; off >>= 1) ss += __shfl_xor(ss, off, 64);
    if (lane == 0) rkn[row] = 1.0f / sqrtf(fmaxf(ss, 1e-30f));
  } else {
    ki[(size_t)row * 64 + lane] = 0;
    if (lane == 0) rkn[row] = 0.f;
  }
}

// Pass 1: i8 screening GEMM (mfma_i32_16x16x64_i8). 128x128 tile, 4 waves,
// 4 blocks/CU. Chunk-XOR swizzle pre-applied to gll16 source (rule #21).
// Writes per-(query, ntile) max score transposed: bmaxT[ntile * NQ + query].
__global__ __launch_bounds__(256, 4) void gemm_screen(
    const int* __restrict__ qi, const int* __restrict__ ki,
    const float* __restrict__ rkn, float* __restrict__ bmaxT) {
  __shared__ __align__(128) char Ab[BM * 128];   // 128 rows x 128 i8 (one K-step)
  __shared__ __align__(128) char Bb[BN * 128];
  __shared__ float cand[BM][2];

  // XCD-clustered decode: same-ntile blocks land on the same XCD (ids = mod 8)
  const int id = blockIdx.x;
  const int mtile = (id >> 3) & 15;
  const int ntile = (id & 7) + 8 * (id >> 7);
  if (ntile >= NTILES) return;

  const int t = threadIdx.x;
  const int w = t >> 6;
  const int lane = t & 63;
  const int wr = w >> 1, wc = w & 1;
  const int q16 = lane >> 4, l16 = lane & 15;
  const int l8 = lane >> 3, c8 = lane & 7;

  // staging: waves 0,1 -> Ab; waves 2,3 -> Bb; each wave 64 rows = 8 gll16.
  const int swz = (c8 ^ l8) * 16;
  int soff[8];
#pragma unroll
  for (int c = 0; c < 8; ++c)
    soff[c] = ((w & 1) * 64 + c * 8 + l8) * 256 + swz;   // bytes (row stride 256B)
  const char* asrc = (const char*)((w < 2) ? qi : ki) +
                     (size_t)(((w < 2) ? mtile : ntile) * 128) * 256;
  char* adst = ((w < 2) ? Ab : Bb) + (w & 1) * 8192;

  i32x4 acc[4][4];
#pragma unroll
  for (int i = 0; i < 4; i++)
#pragma unroll
    for (int j = 0; j < 4; j++) acc[i][j] = (i32x4){0, 0, 0, 0};

  // phys chunk per ks: logical chunk = ks*4 + q16, xor row&7 = l16&7
  int pc[2];
#pragma unroll
  for (int ks = 0; ks < 2; ++ks) pc[ks] = (((ks * 4 + q16) ^ (l16 & 7))) * 16;

#pragma unroll
  for (int s = 0; s < 2; ++s) {            // 2 K-steps of 128
    __syncthreads();
#pragma unroll
    for (int c = 0; c < 8; ++c)
      gll16(asrc + s * 128 + soff[c], adst + c * 1024);
    __syncthreads();
#pragma unroll
    for (int ks = 0; ks < 2; ++ks) {
      i32x4 av[4], bv[4];
#pragma unroll
      for (int i = 0; i < 4; i++)
        av[i] = *(const i32x4*)&Ab[(64 * wr + 16 * i + l16) * 128 + pc[ks]];
#pragma unroll
      for (int j = 0; j < 4; j++)
        bv[j] = *(const i32x4*)&Bb[(64 * wc + 16 * j + l16) * 128 + pc[ks]];
#pragma unroll
      for (int i = 0; i < 4; i++)
#pragma unroll
        for (int j = 0; j < 4; j++)
          acc[i][j] = __builtin_amdgcn_mfma_i32_16x16x64_i8(av[i], bv[j], acc[i][j], 0, 0, 0);
    }
  }

  // Epilogue: per-query-row max of (i32 dot * S^2) * (1/kn) over 128 keys
  int ncol[4];
  float rk[4];
#pragma unroll
  for (int j = 0; j < 4; j++) {
    ncol[j] = ntile * BN + 64 * wc + 16 * j + l16;
    rk[j] = (ncol[j] < NMEM) ? rkn[ncol[j]] * SS2 : 0.f;
  }
#pragma unroll
  for (int i = 0; i < 4; i++) {
#pragma unroll
    for (int r = 0; r < 4; r++) {
      float m = -FLT_MAX;
#pragma unroll
      for (int j = 0; j < 4; j++)
        if (ncol[j] < NMEM) m = fmaxf(m, (float)acc[i][j][r] * rk[j]);
#pragma unroll
      for (int off = 1; off < 16; off <<= 1)
        m = fmaxf(m, __shfl_xor(m, off, 64));
      if (l16 == 0) cand[64 * wr + 16 * i + 4 * q16 + r][wc] = m;
    }
  }
  __syncthreads();
  if (t < BM) {
    float v = fmaxf(cand[t][0], cand[t][1]);
    bmaxT[(size_t)ntile * NQ + mtile * BM + t] = v;  // coalesced
  }
}

// Pass 2, three-level funnel per query:
//   A) global screened max gm over block maxima; thresh = gm - margin
//   B) candidate blocks -> per-ROW i8 screen scores (bit-identical to the MFMA
//      path: i32 dot exact, (float)idot*(rkn*SS2) same rounding) -> row list
//      (~2.3 rows/query expected)
//   C) exact fp64 cosine only for listed rows; argmax w/ low-index tie-break
// margin 1.8e-2*qn = 14.9 sigma of the i8 score error >= 2 x 6.2-sigma bound.
__global__ __launch_bounds__(256) void rescore_gather(
    const float* __restrict__ q, const float* __restrict__ mem,
    const int* __restrict__ qi8, const int* __restrict__ ki8,
    const float* __restrict__ rkn,
    const float* __restrict__ bmaxT, float* __restrict__ out) {
  __shared__ float red2[4];
  __shared__ int blist[64];
  __shared__ int nblk;
  __shared__ int rlist[256];
  __shared__ int nrow;
  __shared__ double wb[4];
  __shared__ int wbi[4];
  __shared__ int widx;

  const int qid = blockIdx.x;
  const int t = threadIdx.x, w = t >> 6, lane = t & 63;

  // lane's 4 query dims (4*lane..4*lane+3): used for ||q|| and phase C
  const float4 qv = *(const float4*)&q[(size_t)qid * 256 + lane * 4];
  float ss = qv.x * qv.x + qv.y * qv.y + qv.z * qv.z + qv.w * qv.w;
#pragma unroll
  for (int off = 32; off >= 1; off >>= 1) ss += __shfl_xor(ss, off, 64);
  const float qn = sqrtf(ss);
  const float margin = 1.8e-2f * qn;

  // lane's 16 query i8-ints for phase B (chunk = lane&3)
  int4 qreg[4];
#pragma unroll
  for (int k = 0; k < 4; ++k)
    qreg[k] = *(const int4*)&qi8[(size_t)qid * 64 + (lane & 3) * 16 + k * 4];

  if (t == 0) { nblk = 0; nrow = 0; }

  // ---- A: global screened max over block maxima ----
  float gm = -FLT_MAX;
  for (int i = t; i < NTILES; i += 256) gm = fmaxf(gm, bmaxT[(size_t)i * NQ + qid]);
#pragma unroll
  for (int off = 32; off >= 1; off >>= 1) gm = fmaxf(gm, __shfl_xor(gm, off, 64));
  if (lane == 0) red2[w] = gm;
  __syncthreads();
  gm = fmaxf(fmaxf(red2[0], red2[1]), fmaxf(red2[2], red2[3]));
  const float thresh = gm - margin;

  for (int i = t; i < NTILES; i += 256)
    if (bmaxT[(size_t)i * NQ + qid] >= thresh) {
      int p = atomicAdd(&nblk, 1);
      if (p < 64) blist[p] = i;
    }
  __syncthreads();
  const int nb = min(nblk, 64);

  // ---- B: per-row i8 screen scores within candidate blocks -> row list ----
  // 4 lanes per row (chunk lane&3 = 16 ints); wave covers 16 rows; 2 passes.
  for (int c = 0; c < nb; ++c) {
    const int nt = blist[c];
#pragma unroll
    for (int pass = 0; pass < 2; ++pass) {
      const int row = nt * 128 + pass * 64 + w * 16 + (lane >> 2);
      int idot = 0;
      if (row < NMEM) {
#pragma unroll
        for (int k = 0; k < 4; ++k) {
          const int4 kv = *(const int4*)&ki8[(size_t)row * 64 + (lane & 3) * 16 + k * 4];
          idot += dot4i8(kv.x, qreg[k].x) + dot4i8(kv.y, qreg[k].y) +
                  dot4i8(kv.z, qreg[k].z) + dot4i8(kv.w, qreg[k].w);
        }
      }
      idot += __shfl_xor(idot, 1, 64);
      idot += __shfl_xor(idot, 2, 64);
      if ((lane & 3) == 0 && row < NMEM) {
        const float sh = (float)idot * (rkn[row] * SS2);  // == gemm's value, bit-exact
        if (sh >= thresh) {
          int p = atomicAdd(&nrow, 1);
          if (p < 256) rlist[p] = row;
        }
      }
    }
  }
  __syncthreads();
  const int nr = min(nrow, 256);

  // ---- C: exact fp64 cosine for listed rows (one row per wave, round-robin) ----
  double bestv = -1e300;
  int bestidx = 0x7fffffff;
  for (int c = w; c < nr; c += 4) {
    const int row = rlist[c];
    const float4 kv = *(const float4*)&mem[(size_t)row * 512 + lane * 4];
    double d = (double)kv.x * qv.x + (double)kv.y * qv.y +
               (double)kv.z * qv.z + (double)kv.w * qv.w;
    double s2 = (double)kv.x * kv.x + (double)kv.y * kv.y +
                (double)kv.z * kv.z + (double)kv.w * kv.w;
#pragma unroll
    for (int off = 32; off >= 1; off >>= 1) {
      d += __shfl_xor(d, off, 64);
      s2 += __shfl_xor(s2, off, 64);
    }
    if (lane == 0) {
      const double score = d / sqrt(s2 > 1e-300 ? s2 : 1e-300);
      if (score > bestv || (score == bestv && row < bestidx)) {
        bestv = score;
        bestidx = row;
      }
    }
  }
  if (lane == 0) { wb[w] = bestv; wbi[w] = bestidx; }
  __syncthreads();
  if (t == 0) {
    double bv = wb[0];
    int bi = wbi[0];
#pragma unroll
    for (int w2 = 1; w2 < 4; ++w2)
      if (wb[w2] > bv || (wb[w2] == bv && wbi[w2] < bi)) {
        bv = wb[w2];
        bi = wbi[w2];
      }
    widx = bi;
  }
  __syncthreads();
  out[(size_t)qid * 256 + t] = mem[(size_t)widx * 512 + 256 + t];
}

extern "C" void kernel_launch(void* const* d_in, const int* in_sizes, int n_in,
                              void* d_out, int out_size, void* d_ws, size_t ws_size,
                              hipStream_t stream) {
  const float* query = (const float*)d_in[0];
  const float* memory = (const float*)d_in[1];
  float* out = (float*)d_out;

  char* p = (char*)d_ws;
  int* qi = (int*)p; p += (size_t)NQ * 64 * 4;          // 2048 x 256 i8
  int* ki = (int*)p; p += (size_t)NPAD * 64 * 4;        // 100096 x 256 i8
  float* rkn = (float*)p; p += (size_t)NPAD * 4;
  float* bmaxT = (float*)p; p += (size_t)NQ * NTILES * 4;

  hipLaunchKernelGGL(convert, dim3(KEYBLOCKS + NQ * MKEY / 1024), dim3(256), 0, stream,
                     query, memory, qi, ki, rkn);
  hipLaunchKernelGGL(gemm_screen, dim3(GRID), dim3(256), 0, stream, qi, ki, rkn, bmaxT);
  hipLaunchKernelGGL(rescore_gather, dim3(NQ), dim3(256), 0, stream,
                     query, memory, qi, ki, rkn, bmaxT, out);
}